// Round 1
// baseline (408.749 us; speedup 1.0000x reference)
//
#include <hip/hip_runtime.h>
#include <hip/hip_cooperative_groups.h>

namespace cg = cooperative_groups;

#define NB     8      // batches
#define NP     2048   // points per cloud
#define NITER  8
#define WPB    32     // workgroups per batch
#define NT     512    // threads per workgroup (8 waves)
#define TSTEPS 32     // targets per lane = NP / 64

__device__ __forceinline__ double det3(const double* X) {
  return X[0]*(X[4]*X[8]-X[5]*X[7])
       + X[1]*(X[5]*X[6]-X[3]*X[8])
       + X[2]*(X[3]*X[7]-X[4]*X[6]);
}

// Orthogonal polar factor of M (== U @ Vh of the SVD), with the reference's
// reflection handling: R = -R when det(R) = -1. Det-scaled Newton iteration,
// fp64, quadratic convergence (14 iters is overkill-safe).
__device__ void polar3x3(const double* M, double* R) {
  double X[9];
  #pragma unroll
  for (int i = 0; i < 9; ++i) X[i] = M[i];
  for (int it = 0; it < 14; ++it) {
    const double C0 = X[4]*X[8]-X[5]*X[7];
    const double C1 = X[5]*X[6]-X[3]*X[8];
    const double C2 = X[3]*X[7]-X[4]*X[6];
    const double C3 = X[2]*X[7]-X[1]*X[8];
    const double C4 = X[0]*X[8]-X[2]*X[6];
    const double C5 = X[1]*X[6]-X[0]*X[7];
    const double C6 = X[1]*X[5]-X[2]*X[4];
    const double C7 = X[2]*X[3]-X[0]*X[5];
    const double C8 = X[0]*X[4]-X[1]*X[3];
    const double det = X[0]*C0 + X[1]*C1 + X[2]*C2;
    const double ad  = fabs(det);
    const double g   = (ad > 1e-300) ? cbrt(1.0 / ad) : 1.0;  // |det|^(-1/3)
    const double h   = 0.5 / (g * det);   // X_next = 0.5*g*X + C/(2*g*det)
    const double gh  = 0.5 * g;
    X[0]=gh*X[0]+h*C0; X[1]=gh*X[1]+h*C1; X[2]=gh*X[2]+h*C2;
    X[3]=gh*X[3]+h*C3; X[4]=gh*X[4]+h*C4; X[5]=gh*X[5]+h*C5;
    X[6]=gh*X[6]+h*C6; X[7]=gh*X[7]+h*C7; X[8]=gh*X[8]+h*C8;
  }
  const double s = (det3(X) < 0.0) ? -1.0 : 1.0;
  #pragma unroll
  for (int i = 0; i < 9; ++i) R[i] = s * X[i];
}

__global__ __launch_bounds__(NT, 2)
void icp_kernel(const float* __restrict__ src, const float* __restrict__ tgt,
                float* __restrict__ out, float* __restrict__ ws)
{
  cg::grid_group grid = cg::this_grid();

  __shared__ float4 s_tgt[NP];        // 32 KB, loaded once, constant across iters
  __shared__ float  s_part[8][16];    // per-wave partial sums
  __shared__ double s_red[15];        // batch-level reduced sums
  __shared__ float  s_rt[12];         // R (9) + t (3) broadcast

  const int tid   = threadIdx.x;
  const int wg    = blockIdx.x;
  const int batch = wg / WPB;
  const int w     = wg % WPB;
  const int wave  = tid >> 6;
  const int lane  = tid & 63;

  // ---- stage targets in LDS as float4 ----
  const float* tb = tgt + (size_t)batch * NP * 3;
  for (int i = tid; i < NP; i += NT)
    s_tgt[i] = make_float4(tb[3*i+0], tb[3*i+1], tb[3*i+2], 0.f);

  // ---- this wave's 8 temporal points (replicated across lanes) ----
  const int r0 = w * 64 + wave * 8;   // ref base within batch
  const float* sb = src + (size_t)(batch * NP + r0) * 3;
  float px[8], py[8], pz[8];
  #pragma unroll
  for (int r = 0; r < 8; ++r) {
    px[r] = sb[3*r+0]; py[r] = sb[3*r+1]; pz[r] = sb[3*r+2];
  }
  __syncthreads();

  for (int iter = 0; iter < NITER; ++iter) {
    // ---- KNN: wave's 8 refs vs all 2048 targets (lane b scans j = k*64+b) ----
    float bd[8]; int bj[8];
    #pragma unroll
    for (int r = 0; r < 8; ++r) { bd[r] = 3.4e38f; bj[r] = 0; }
    #pragma unroll 2
    for (int k = 0; k < TSTEPS; ++k) {
      const int j = k * 64 + lane;
      const float4 tp = s_tgt[j];
      #pragma unroll
      for (int r = 0; r < 8; ++r) {
        const float dx = px[r] - tp.x;
        const float dy = py[r] - tp.y;
        const float dz = pz[r] - tp.z;
        const float d  = fmaf(dz, dz, fmaf(dy, dy, dx*dx));
        if (d < bd[r]) { bd[r] = d; bj[r] = j; }   // strict < keeps first index
      }
    }
    // cross-lane argmin, tie -> smaller index (matches argmin first-index rule)
    #pragma unroll
    for (int r = 0; r < 8; ++r) {
      #pragma unroll
      for (int sh = 0; sh < 6; ++sh) {
        const int   off = 32 >> sh;
        const float od  = __shfl_xor(bd[r], off);
        const int   oj  = __shfl_xor(bj[r], off);
        if (od < bd[r] || (od == bd[r] && oj < bj[r])) { bd[r] = od; bj[r] = oj; }
      }
    }

    // ---- per-wave Kabsch partials (identical in every lane; lane 0 writes) ----
    {
      float S[15];
      #pragma unroll
      for (int i = 0; i < 15; ++i) S[i] = 0.f;
      #pragma unroll
      for (int r = 0; r < 8; ++r) {
        const float4 tm = s_tgt[bj[r]];       // broadcast read
        S[0]+=px[r]; S[1]+=py[r]; S[2]+=pz[r];
        S[3]+=tm.x;  S[4]+=tm.y;  S[5]+=tm.z;
        S[6] +=tm.x*px[r]; S[7] +=tm.x*py[r]; S[8] +=tm.x*pz[r];
        S[9] +=tm.y*px[r]; S[10]+=tm.y*py[r]; S[11]+=tm.y*pz[r];
        S[12]+=tm.z*px[r]; S[13]+=tm.z*py[r]; S[14]+=tm.z*pz[r];
      }
      if (lane == 0) {
        #pragma unroll
        for (int i = 0; i < 15; ++i) s_part[wave][i] = S[i];
      }
    }
    __syncthreads();
    if (tid < 15) {
      float a = 0.f;
      #pragma unroll
      for (int q = 0; q < 8; ++q) a += s_part[q][tid];
      ws[((((iter & 1) * NB + batch) * WPB + w) << 4) + tid] = a;
    }

    grid.sync();

    // ---- every WG redundantly reduces its batch (deterministic, no 2nd sync) ----
    if (tid < 15) {
      double a = 0.0;
      const float* b0 = ws + ((((iter & 1) * NB + batch) * WPB) << 4) + tid;
      for (int q = 0; q < WPB; ++q) a += (double)b0[q << 4];
      s_red[tid] = a;
    }
    __syncthreads();
    if (tid == 0) {
      const double inv = 1.0 / (double)NP;
      double cs0=s_red[0]*inv, cs1=s_red[1]*inv, cs2=s_red[2]*inv;
      double ct0=s_red[3]*inv, ct1=s_red[4]*inv, ct2=s_red[5]*inv;
      double M[9];
      M[0]=s_red[6] -(double)NP*ct0*cs0; M[1]=s_red[7] -(double)NP*ct0*cs1; M[2]=s_red[8] -(double)NP*ct0*cs2;
      M[3]=s_red[9] -(double)NP*ct1*cs0; M[4]=s_red[10]-(double)NP*ct1*cs1; M[5]=s_red[11]-(double)NP*ct1*cs2;
      M[6]=s_red[12]-(double)NP*ct2*cs0; M[7]=s_red[13]-(double)NP*ct2*cs1; M[8]=s_red[14]-(double)NP*ct2*cs2;
      double R[9]; polar3x3(M, R);
      #pragma unroll
      for (int i = 0; i < 9; ++i) s_rt[i] = (float)R[i];
      s_rt[9]  = (float)(ct0 - (R[0]*cs0 + R[1]*cs1 + R[2]*cs2));
      s_rt[10] = (float)(ct1 - (R[3]*cs0 + R[4]*cs1 + R[5]*cs2));
      s_rt[11] = (float)(ct2 - (R[6]*cs0 + R[7]*cs1 + R[8]*cs2));
    }
    __syncthreads();

    // ---- apply transform to this wave's temporal points (fp32, like ref) ----
    {
      const float R00=s_rt[0],R01=s_rt[1],R02=s_rt[2],
                  R10=s_rt[3],R11=s_rt[4],R12=s_rt[5],
                  R20=s_rt[6],R21=s_rt[7],R22=s_rt[8],
                  t0=s_rt[9], t1=s_rt[10], t2=s_rt[11];
      #pragma unroll
      for (int r = 0; r < 8; ++r) {
        const float nx = t0 + R00*px[r] + R01*py[r] + R02*pz[r];
        const float ny = t1 + R10*px[r] + R11*py[r] + R12*pz[r];
        const float nz = t2 + R20*px[r] + R21*py[r] + R22*pz[r];
        px[r]=nx; py[r]=ny; pz[r]=nz;
      }
    }
  }

  // ---- final Kabsch: original source -> final temporal ----
  {
    float S[15];
    #pragma unroll
    for (int i = 0; i < 15; ++i) S[i] = 0.f;
    const float* sb2 = src + (size_t)(batch * NP + r0) * 3;
    #pragma unroll
    for (int r = 0; r < 8; ++r) {
      const float ox = sb2[3*r+0], oy = sb2[3*r+1], oz = sb2[3*r+2];
      S[0]+=ox; S[1]+=oy; S[2]+=oz;
      S[3]+=px[r]; S[4]+=py[r]; S[5]+=pz[r];
      S[6] +=px[r]*ox; S[7] +=px[r]*oy; S[8] +=px[r]*oz;
      S[9] +=py[r]*ox; S[10]+=py[r]*oy; S[11]+=py[r]*oz;
      S[12]+=pz[r]*ox; S[13]+=pz[r]*oy; S[14]+=pz[r]*oz;
    }
    if (lane == 0) {
      #pragma unroll
      for (int i = 0; i < 15; ++i) s_part[wave][i] = S[i];
    }
  }
  __syncthreads();
  if (tid < 15) {
    float a = 0.f;
    #pragma unroll
    for (int q = 0; q < 8; ++q) a += s_part[q][tid];
    // buffer 0 is safe here: last read of buf0 finished before sync #8
    ws[(((0 * NB + batch) * WPB + w) << 4) + tid] = a;
  }

  grid.sync();

  if (w == 0) {
    if (tid < 15) {
      double a = 0.0;
      const float* b0 = ws + (((0 * NB + batch) * WPB) << 4) + tid;
      for (int q = 0; q < WPB; ++q) a += (double)b0[q << 4];
      s_red[tid] = a;
    }
    __syncthreads();
    if (tid == 0) {
      const double inv = 1.0 / (double)NP;
      double cs0=s_red[0]*inv, cs1=s_red[1]*inv, cs2=s_red[2]*inv;
      double ct0=s_red[3]*inv, ct1=s_red[4]*inv, ct2=s_red[5]*inv;
      double M[9];
      M[0]=s_red[6] -(double)NP*ct0*cs0; M[1]=s_red[7] -(double)NP*ct0*cs1; M[2]=s_red[8] -(double)NP*ct0*cs2;
      M[3]=s_red[9] -(double)NP*ct1*cs0; M[4]=s_red[10]-(double)NP*ct1*cs1; M[5]=s_red[11]-(double)NP*ct1*cs2;
      M[6]=s_red[12]-(double)NP*ct2*cs0; M[7]=s_red[13]-(double)NP*ct2*cs1; M[8]=s_red[14]-(double)NP*ct2*cs2;
      double R[9]; polar3x3(M, R);
      const double t0 = ct0 - (R[0]*cs0 + R[1]*cs1 + R[2]*cs2);
      const double t1 = ct1 - (R[3]*cs0 + R[4]*cs1 + R[5]*cs2);
      const double t2 = ct2 - (R[6]*cs0 + R[7]*cs1 + R[8]*cs2);
      float* ob = out + batch * 12;
      ob[0]=(float)R[0]; ob[1]=(float)R[1]; ob[2] =(float)R[2]; ob[3] =(float)t0;
      ob[4]=(float)R[3]; ob[5]=(float)R[4]; ob[6] =(float)R[5]; ob[7] =(float)t1;
      ob[8]=(float)R[6]; ob[9]=(float)R[7]; ob[10]=(float)R[8]; ob[11]=(float)t2;
    }
  }
}

extern "C" void kernel_launch(void* const* d_in, const int* in_sizes, int n_in,
                              void* d_out, int out_size, void* d_ws, size_t ws_size,
                              hipStream_t stream)
{
  const float* src = (const float*)d_in[0];
  const float* tgt = (const float*)d_in[1];
  float* out = (float*)d_out;
  float* ws  = (float*)d_ws;

  void* args[] = { (void*)&src, (void*)&tgt, (void*)&out, (void*)&ws };
  hipLaunchCooperativeKernel(reinterpret_cast<void*>(icp_kernel),
                             dim3(NB * WPB), dim3(NT), args, 0, stream);
}

// Round 2
// 232.344 us; speedup vs baseline: 1.7592x; 1.7592x over previous
//
#include <hip/hip_runtime.h>

#define NB     8      // batches
#define NP     2048   // points per cloud
#define NITER  8
#define WPB    32     // workgroups per batch
#define NT     512    // threads per workgroup (8 waves)
#define TSTEPS 32     // targets per lane = NP / 64

// ws layout (floats):
//   partials: [2 parity][NB][WPB][16]  = 8192 floats (32 KB)
//   barrier : [NB][32] uints           at float offset 8192 (1 KB), memset(0) per call
#define BAR_OFF_FLOATS 8192

// Orthogonal polar factor of M (== U @ Vh of the SVD) in fp32, with the
// reference's reflection handling (R = -R when det = -1). Det-scaled Newton,
// quadratic convergence; 14 iters is overkill-safe, costs ~0.1 us on one lane.
__device__ void polar3x3f(const float* Min, float* R) {
  float X[9];
  #pragma unroll
  for (int i = 0; i < 9; ++i) X[i] = Min[i];
  #pragma unroll 1
  for (int it = 0; it < 14; ++it) {
    const float C0 = X[4]*X[8]-X[5]*X[7];
    const float C1 = X[5]*X[6]-X[3]*X[8];
    const float C2 = X[3]*X[7]-X[4]*X[6];
    const float C3 = X[2]*X[7]-X[1]*X[8];
    const float C4 = X[0]*X[8]-X[2]*X[6];
    const float C5 = X[1]*X[6]-X[0]*X[7];
    const float C6 = X[1]*X[5]-X[2]*X[4];
    const float C7 = X[2]*X[3]-X[0]*X[5];
    const float C8 = X[0]*X[4]-X[1]*X[3];
    const float det = X[0]*C0 + X[1]*C1 + X[2]*C2;
    const float ad  = fabsf(det);
    const float g   = (ad > 1e-30f) ? exp2f(-0.33333333333f * log2f(ad)) : 1.0f;
    const float ds  = (ad > 1e-30f) ? det : 1e-30f;
    const float h   = 0.5f / (g * ds);     // X' = 0.5*g*X + cof(X)/(2*g*det)
    const float gh  = 0.5f * g;
    X[0]=gh*X[0]+h*C0; X[1]=gh*X[1]+h*C1; X[2]=gh*X[2]+h*C2;
    X[3]=gh*X[3]+h*C3; X[4]=gh*X[4]+h*C4; X[5]=gh*X[5]+h*C5;
    X[6]=gh*X[6]+h*C6; X[7]=gh*X[7]+h*C7; X[8]=gh*X[8]+h*C8;
  }
  const float d = X[0]*(X[4]*X[8]-X[5]*X[7])
                + X[1]*(X[5]*X[6]-X[3]*X[8])
                + X[2]*(X[3]*X[7]-X[4]*X[6]);
  const float s = (d < 0.0f) ? -1.0f : 1.0f;
  #pragma unroll
  for (int i = 0; i < 9; ++i) R[i] = s * X[i];
}

// Sense-reversing barrier among the WPB workgroups of one batch.
// bar[0] = arrival counter (reset by last arriver), bar[1] = sense (monotone).
// Requires co-residency (cooperative launch) and bar zeroed before the kernel.
__device__ __forceinline__ void batch_barrier(unsigned* bar, unsigned sense, int tid) {
  __syncthreads();   // all WG threads done with prior work, stores retired
  if (tid == 0) {
    unsigned arrived = __hip_atomic_fetch_add(&bar[0], 1u,
                         __ATOMIC_ACQ_REL, __HIP_MEMORY_SCOPE_AGENT);
    if (arrived == WPB - 1u) {
      __hip_atomic_store(&bar[0], 0u, __ATOMIC_RELAXED, __HIP_MEMORY_SCOPE_AGENT);
      __hip_atomic_store(&bar[1], sense, __ATOMIC_RELEASE, __HIP_MEMORY_SCOPE_AGENT);
    } else {
      while (__hip_atomic_load(&bar[1], __ATOMIC_ACQUIRE, __HIP_MEMORY_SCOPE_AGENT) < sense)
        __builtin_amdgcn_s_sleep(1);
    }
  }
  __syncthreads();
}

__global__ __launch_bounds__(NT, 2)
void icp_kernel(const float* __restrict__ src, const float* __restrict__ tgt,
                float* __restrict__ out, float* __restrict__ ws)
{
  __shared__ float4 s_tgt[NP];        // 32 KB: {x,y,z, 0.5*|t|^2}, constant across iters
  __shared__ float  s_part[8][16];    // per-wave partial sums
  __shared__ double s_red[15];        // batch-level reduced sums
  __shared__ float  s_rt[12];         // R (9) + t (3) broadcast

  const int tid   = threadIdx.x;
  const int wg    = blockIdx.x;
  const int batch = wg / WPB;
  const int w     = wg % WPB;
  const int wave  = tid >> 6;
  const int lane  = tid & 63;

  unsigned* bar = (unsigned*)(ws + BAR_OFF_FLOATS) + batch * 32;

  // ---- stage targets in LDS; .w = 0.5*|t|^2 for the score trick ----
  const float* tb = tgt + (size_t)batch * NP * 3;
  for (int i = tid; i < NP; i += NT) {
    const float tx = tb[3*i+0], ty = tb[3*i+1], tz = tb[3*i+2];
    s_tgt[i] = make_float4(tx, ty, tz, 0.5f*(tx*tx + ty*ty + tz*tz));
  }

  // ---- this wave's 8 temporal points (replicated across lanes) ----
  const int r0 = w * 64 + wave * 8;
  const float* sb = src + (size_t)(batch * NP + r0) * 3;
  float px[8], py[8], pz[8];
  #pragma unroll
  for (int r = 0; r < 8; ++r) {
    px[r] = sb[3*r+0]; py[r] = sb[3*r+1]; pz[r] = sb[3*r+2];
  }
  __syncthreads();

  unsigned sense = 0;

  for (int round = 0; round < NITER; ++round) {
    // ---- KNN via score = 0.5|t|^2 - p.t  (argmin(score) == argmin(dist)) ----
    float bs[8]; int bj[8];
    #pragma unroll
    for (int r = 0; r < 8; ++r) { bs[r] = 3.4e38f; bj[r] = 0; }
    #pragma unroll 4
    for (int k = 0; k < TSTEPS; ++k) {
      const int j = k * 64 + lane;
      const float4 tp = s_tgt[j];
      #pragma unroll
      for (int r = 0; r < 8; ++r) {
        const float sc = fmaf(-px[r], tp.x, fmaf(-py[r], tp.y, fmaf(-pz[r], tp.z, tp.w)));
        if (sc < bs[r]) { bs[r] = sc; bj[r] = j; }   // strict < keeps first index
      }
    }
    // cross-lane argmin, tie -> smaller index
    #pragma unroll
    for (int r = 0; r < 8; ++r) {
      #pragma unroll
      for (int sh = 0; sh < 6; ++sh) {
        const int   off = 32 >> sh;
        const float od  = __shfl_xor(bs[r], off);
        const int   oj  = __shfl_xor(bj[r], off);
        if (od < bs[r] || (od == bs[r] && oj < bj[r])) { bs[r] = od; bj[r] = oj; }
      }
    }

    // ---- per-wave Kabsch partials (identical in every lane; lane 0 writes) ----
    {
      float S[15];
      #pragma unroll
      for (int i = 0; i < 15; ++i) S[i] = 0.f;
      #pragma unroll
      for (int r = 0; r < 8; ++r) {
        const float4 tm = s_tgt[bj[r]];
        S[0]+=px[r]; S[1]+=py[r]; S[2]+=pz[r];
        S[3]+=tm.x;  S[4]+=tm.y;  S[5]+=tm.z;
        S[6] +=tm.x*px[r]; S[7] +=tm.x*py[r]; S[8] +=tm.x*pz[r];
        S[9] +=tm.y*px[r]; S[10]+=tm.y*py[r]; S[11]+=tm.y*pz[r];
        S[12]+=tm.z*px[r]; S[13]+=tm.z*py[r]; S[14]+=tm.z*pz[r];
      }
      if (lane == 0) {
        #pragma unroll
        for (int i = 0; i < 15; ++i) s_part[wave][i] = S[i];
      }
    }
    __syncthreads();
    if (tid < 15) {
      float a = 0.f;
      #pragma unroll
      for (int q = 0; q < 8; ++q) a += s_part[q][tid];
      float* dst = ws + ((((round & 1) * NB + batch) * WPB + w) << 4) + tid;
      __hip_atomic_store(dst, a, __ATOMIC_RELAXED, __HIP_MEMORY_SCOPE_AGENT);
    }

    ++sense;
    batch_barrier(bar, sense, tid);

    // ---- every WG redundantly reduces its batch (no departure barrier) ----
    if (tid < 15) {
      double a = 0.0;
      float* b0 = ws + (((round & 1) * NB + batch) * WPB << 4) + tid;
      for (int q = 0; q < WPB; ++q)
        a += (double)__hip_atomic_load(b0 + (q << 4), __ATOMIC_RELAXED, __HIP_MEMORY_SCOPE_AGENT);
      s_red[tid] = a;
    }
    __syncthreads();
    if (tid == 0) {
      const double inv = 1.0 / (double)NP;
      const double cs0=s_red[0]*inv, cs1=s_red[1]*inv, cs2=s_red[2]*inv;
      const double ct0=s_red[3]*inv, ct1=s_red[4]*inv, ct2=s_red[5]*inv;
      float M[9];
      M[0]=(float)(s_red[6] -(double)NP*ct0*cs0); M[1]=(float)(s_red[7] -(double)NP*ct0*cs1); M[2]=(float)(s_red[8] -(double)NP*ct0*cs2);
      M[3]=(float)(s_red[9] -(double)NP*ct1*cs0); M[4]=(float)(s_red[10]-(double)NP*ct1*cs1); M[5]=(float)(s_red[11]-(double)NP*ct1*cs2);
      M[6]=(float)(s_red[12]-(double)NP*ct2*cs0); M[7]=(float)(s_red[13]-(double)NP*ct2*cs1); M[8]=(float)(s_red[14]-(double)NP*ct2*cs2);
      float R[9]; polar3x3f(M, R);
      #pragma unroll
      for (int i = 0; i < 9; ++i) s_rt[i] = R[i];
      s_rt[9]  = (float)(ct0 - ((double)R[0]*cs0 + (double)R[1]*cs1 + (double)R[2]*cs2));
      s_rt[10] = (float)(ct1 - ((double)R[3]*cs0 + (double)R[4]*cs1 + (double)R[5]*cs2));
      s_rt[11] = (float)(ct2 - ((double)R[6]*cs0 + (double)R[7]*cs1 + (double)R[8]*cs2));
    }
    __syncthreads();

    // ---- apply transform to this wave's temporal points (fp32, like ref) ----
    {
      const float R00=s_rt[0],R01=s_rt[1],R02=s_rt[2],
                  R10=s_rt[3],R11=s_rt[4],R12=s_rt[5],
                  R20=s_rt[6],R21=s_rt[7],R22=s_rt[8],
                  t0=s_rt[9], t1=s_rt[10], t2=s_rt[11];
      #pragma unroll
      for (int r = 0; r < 8; ++r) {
        const float nx = t0 + R00*px[r] + R01*py[r] + R02*pz[r];
        const float ny = t1 + R10*px[r] + R11*py[r] + R12*pz[r];
        const float nz = t2 + R20*px[r] + R21*py[r] + R22*pz[r];
        px[r]=nx; py[r]=ny; pz[r]=nz;
      }
    }
  }

  // ---- final Kabsch: original source -> final temporal (round 8, parity 0) ----
  {
    float S[15];
    #pragma unroll
    for (int i = 0; i < 15; ++i) S[i] = 0.f;
    const float* sb2 = src + (size_t)(batch * NP + r0) * 3;
    #pragma unroll
    for (int r = 0; r < 8; ++r) {
      const float ox = sb2[3*r+0], oy = sb2[3*r+1], oz = sb2[3*r+2];
      S[0]+=ox; S[1]+=oy; S[2]+=oz;
      S[3]+=px[r]; S[4]+=py[r]; S[5]+=pz[r];
      S[6] +=px[r]*ox; S[7] +=px[r]*oy; S[8] +=px[r]*oz;
      S[9] +=py[r]*ox; S[10]+=py[r]*oy; S[11]+=py[r]*oz;
      S[12]+=pz[r]*ox; S[13]+=pz[r]*oy; S[14]+=pz[r]*oz;
    }
    if (lane == 0) {
      #pragma unroll
      for (int i = 0; i < 15; ++i) s_part[wave][i] = S[i];
    }
  }
  __syncthreads();
  if (tid < 15) {
    float a = 0.f;
    #pragma unroll
    for (int q = 0; q < 8; ++q) a += s_part[q][tid];
    float* dst = ws + (((0 * NB + batch) * WPB + w) << 4) + tid;
    __hip_atomic_store(dst, a, __ATOMIC_RELAXED, __HIP_MEMORY_SCOPE_AGENT);
  }

  ++sense;
  batch_barrier(bar, sense, tid);

  if (w == 0) {
    if (tid < 15) {
      double a = 0.0;
      float* b0 = ws + ((0 * NB + batch) * WPB << 4) + tid;
      for (int q = 0; q < WPB; ++q)
        a += (double)__hip_atomic_load(b0 + (q << 4), __ATOMIC_RELAXED, __HIP_MEMORY_SCOPE_AGENT);
      s_red[tid] = a;
    }
    __syncthreads();
    if (tid == 0) {
      const double inv = 1.0 / (double)NP;
      const double cs0=s_red[0]*inv, cs1=s_red[1]*inv, cs2=s_red[2]*inv;
      const double ct0=s_red[3]*inv, ct1=s_red[4]*inv, ct2=s_red[5]*inv;
      float M[9];
      M[0]=(float)(s_red[6] -(double)NP*ct0*cs0); M[1]=(float)(s_red[7] -(double)NP*ct0*cs1); M[2]=(float)(s_red[8] -(double)NP*ct0*cs2);
      M[3]=(float)(s_red[9] -(double)NP*ct1*cs0); M[4]=(float)(s_red[10]-(double)NP*ct1*cs1); M[5]=(float)(s_red[11]-(double)NP*ct1*cs2);
      M[6]=(float)(s_red[12]-(double)NP*ct2*cs0); M[7]=(float)(s_red[13]-(double)NP*ct2*cs1); M[8]=(float)(s_red[14]-(double)NP*ct2*cs2);
      float R[9]; polar3x3f(M, R);
      const double t0 = ct0 - ((double)R[0]*cs0 + (double)R[1]*cs1 + (double)R[2]*cs2);
      const double t1 = ct1 - ((double)R[3]*cs0 + (double)R[4]*cs1 + (double)R[5]*cs2);
      const double t2 = ct2 - ((double)R[6]*cs0 + (double)R[7]*cs1 + (double)R[8]*cs2);
      float* ob = out + batch * 12;
      ob[0]=R[0]; ob[1]=R[1]; ob[2] =R[2]; ob[3] =(float)t0;
      ob[4]=R[3]; ob[5]=R[4]; ob[6] =R[5]; ob[7] =(float)t1;
      ob[8]=R[6]; ob[9]=R[7]; ob[10]=R[8]; ob[11]=(float)t2;
    }
  }
}

extern "C" void kernel_launch(void* const* d_in, const int* in_sizes, int n_in,
                              void* d_out, int out_size, void* d_ws, size_t ws_size,
                              hipStream_t stream)
{
  const float* src = (const float*)d_in[0];
  const float* tgt = (const float*)d_in[1];
  float* out = (float*)d_out;
  float* ws  = (float*)d_ws;

  // zero the barrier region (counters+senses) every call: deterministic from
  // poisoned ws, and replay-safe. Async memset is graph-capturable.
  hipMemsetAsync((char*)d_ws + BAR_OFF_FLOATS * sizeof(float), 0,
                 NB * 32 * sizeof(unsigned), stream);

  void* args[] = { (void*)&src, (void*)&tgt, (void*)&out, (void*)&ws };
  hipLaunchCooperativeKernel(reinterpret_cast<void*>(icp_kernel),
                             dim3(NB * WPB), dim3(NT), args, 0, stream);
}

// Round 3
// 212.448 us; speedup vs baseline: 1.9240x; 1.0937x over previous
//
#include <hip/hip_runtime.h>

#define NB     8      // batches
#define NP     2048   // points per cloud
#define NITER  8
#define WPB    32     // workgroups per batch
#define NT     512    // threads per workgroup (8 waves)
#define TSTEPS 32     // targets per lane = NP / 64

// ws layout: [2 parity][NB][WPB][16] floats.
// slot[0..14] = Kabsch partials (relaxed agent stores), slot[15] = uint sentinel
// (release agent store, value = round+1; exact-equality polling).
// Entire 32 KB region is hipMemsetAsync'd to 0 each call -> replay-deterministic.

// Orthogonal polar factor of M (== U @ Vh of the SVD) in fp32, with the
// reference's reflection handling (R = -R when det = -1). Det-scaled Newton.
__device__ void polar3x3f(const float* Min, float* R) {
  float X[9];
  #pragma unroll
  for (int i = 0; i < 9; ++i) X[i] = Min[i];
  #pragma unroll 1
  for (int it = 0; it < 12; ++it) {
    const float C0 = X[4]*X[8]-X[5]*X[7];
    const float C1 = X[5]*X[6]-X[3]*X[8];
    const float C2 = X[3]*X[7]-X[4]*X[6];
    const float C3 = X[2]*X[7]-X[1]*X[8];
    const float C4 = X[0]*X[8]-X[2]*X[6];
    const float C5 = X[1]*X[6]-X[0]*X[7];
    const float C6 = X[1]*X[5]-X[2]*X[4];
    const float C7 = X[2]*X[3]-X[0]*X[5];
    const float C8 = X[0]*X[4]-X[1]*X[3];
    const float det = X[0]*C0 + X[1]*C1 + X[2]*C2;
    const float ad  = fabsf(det);
    const float g   = (ad > 1e-30f) ? exp2f(-0.33333333333f * log2f(ad)) : 1.0f;
    const float ds  = (ad > 1e-30f) ? det : 1e-30f;
    const float h   = 0.5f / (g * ds);     // X' = 0.5*g*X + cof(X)/(2*g*det)
    const float gh  = 0.5f * g;
    X[0]=gh*X[0]+h*C0; X[1]=gh*X[1]+h*C1; X[2]=gh*X[2]+h*C2;
    X[3]=gh*X[3]+h*C3; X[4]=gh*X[4]+h*C4; X[5]=gh*X[5]+h*C5;
    X[6]=gh*X[6]+h*C6; X[7]=gh*X[7]+h*C7; X[8]=gh*X[8]+h*C8;
  }
  const float d = X[0]*(X[4]*X[8]-X[5]*X[7])
                + X[1]*(X[5]*X[6]-X[3]*X[8])
                + X[2]*(X[3]*X[7]-X[4]*X[6]);
  const float s = (d < 0.0f) ? -1.0f : 1.0f;
  #pragma unroll
  for (int i = 0; i < 9; ++i) R[i] = s * X[i];
}

__global__ __launch_bounds__(NT, 2)
void icp_kernel(const float* __restrict__ src, const float* __restrict__ tgt,
                float* __restrict__ out, float* __restrict__ ws)
{
  __shared__ float4 s_tgt[NP];        // 32 KB: {x,y,z, 0.5*|t|^2}, constant across iters
  __shared__ float  s_part[8][16];    // per-wave partial sums
  __shared__ float  s_rt[12];         // R (9) + t (3) broadcast

  const int tid   = threadIdx.x;
  const int wg    = blockIdx.x;
  const int batch = wg & 7;           // XCD-swizzle: one batch's WGs share an XCD
  const int w     = wg >> 3;
  const int wave  = tid >> 6;
  const int lane  = tid & 63;

  // ---- stage targets in LDS; .w = 0.5*|t|^2 for the score trick ----
  const float* tb = tgt + (size_t)batch * NP * 3;
  for (int i = tid; i < NP; i += NT) {
    const float tx = tb[3*i+0], ty = tb[3*i+1], tz = tb[3*i+2];
    s_tgt[i] = make_float4(tx, ty, tz, 0.5f*(tx*tx + ty*ty + tz*tz));
  }

  // ---- this wave's 8 temporal points (replicated across lanes) ----
  const int r0 = w * 64 + wave * 8;
  const float* sb = src + (size_t)(batch * NP + r0) * 3;
  float px[8], py[8], pz[8];
  #pragma unroll
  for (int r = 0; r < 8; ++r) {
    px[r] = sb[3*r+0]; py[r] = sb[3*r+1]; pz[r] = sb[3*r+2];
  }
  __syncthreads();

  for (int round = 0; round < NITER; ++round) {
    const int      par  = round & 1;
    const unsigned want = (unsigned)(round + 1);

    // ---- KNN via score = 0.5|t|^2 - p.t  (argmin(score) == argmin(dist)) ----
    float bs[8]; int bj[8];
    #pragma unroll
    for (int r = 0; r < 8; ++r) { bs[r] = 3.4e38f; bj[r] = 0; }
    #pragma unroll 4
    for (int k = 0; k < TSTEPS; ++k) {
      const int j = k * 64 + lane;
      const float4 tp = s_tgt[j];
      #pragma unroll
      for (int r = 0; r < 8; ++r) {
        const float sc = fmaf(-px[r], tp.x, fmaf(-py[r], tp.y, fmaf(-pz[r], tp.z, tp.w)));
        if (sc < bs[r]) { bs[r] = sc; bj[r] = j; }   // strict < keeps first index
      }
    }
    // cross-lane argmin, tie -> smaller index (matches argmin first-index rule)
    #pragma unroll
    for (int r = 0; r < 8; ++r) {
      #pragma unroll
      for (int sh = 0; sh < 6; ++sh) {
        const int   off = 32 >> sh;
        const float od  = __shfl_xor(bs[r], off);
        const int   oj  = __shfl_xor(bj[r], off);
        if (od < bs[r] || (od == bs[r] && oj < bj[r])) { bs[r] = od; bj[r] = oj; }
      }
    }

    // ---- per-wave Kabsch partials (identical in every lane; lane 0 writes) ----
    {
      float S[15];
      #pragma unroll
      for (int i = 0; i < 15; ++i) S[i] = 0.f;
      #pragma unroll
      for (int r = 0; r < 8; ++r) {
        const float4 tm = s_tgt[bj[r]];
        S[0]+=px[r]; S[1]+=py[r]; S[2]+=pz[r];
        S[3]+=tm.x;  S[4]+=tm.y;  S[5]+=tm.z;
        S[6] +=tm.x*px[r]; S[7] +=tm.x*py[r]; S[8] +=tm.x*pz[r];
        S[9] +=tm.y*px[r]; S[10]+=tm.y*py[r]; S[11]+=tm.y*pz[r];
        S[12]+=tm.z*px[r]; S[13]+=tm.z*py[r]; S[14]+=tm.z*pz[r];
      }
      if (lane == 0) {
        #pragma unroll
        for (int i = 0; i < 15; ++i) s_part[wave][i] = S[i];
      }
    }
    __syncthreads();

    if (wave == 0) {
      // ---- fold 8 wave-partials across LDS with shuffles ----
      const int comp = lane & 15, grp = lane >> 4;
      float v = (comp < 15) ? (s_part[2*grp][comp] + s_part[2*grp+1][comp]) : 0.f;
      v += __shfl_xor(v, 16);
      v += __shfl_xor(v, 32);          // all lanes: total for their comp

      // ---- lane 0 publishes: 15 relaxed stores + release sentinel (no RMW) ----
      float Sv[15];
      #pragma unroll
      for (int i = 0; i < 15; ++i) Sv[i] = __shfl(v, i);
      float* slotMine = ws + ((((size_t)par * NB + batch) * WPB + w) << 4);
      if (lane == 0) {
        #pragma unroll
        for (int i = 0; i < 15; ++i)
          __hip_atomic_store(&slotMine[i], Sv[i], __ATOMIC_RELAXED, __HIP_MEMORY_SCOPE_AGENT);
        __hip_atomic_store((unsigned*)slotMine + 15, want,
                           __ATOMIC_RELEASE, __HIP_MEMORY_SCOPE_AGENT);
      }

      // ---- distributed poll: lane q watches slot q (parallel, no contention) ----
      float* base = ws + (((size_t)par * NB + batch) * WPB << 4);
      unsigned* sentq = (unsigned*)(base + ((size_t)lane << 4)) + 15;
      int ok;
      do {
        ok = (lane >= WPB) ||
             (__hip_atomic_load(sentq, __ATOMIC_ACQUIRE, __HIP_MEMORY_SCOPE_AGENT) == want);
      } while (!__all(ok));

      // ---- lane q reads its slot's 15 floats; shuffle-reduce over 32 lanes ----
      const float* slotq = base + ((size_t)lane << 4);
      double d[15];
      #pragma unroll
      for (int i = 0; i < 15; ++i)
        d[i] = (lane < WPB)
             ? (double)__hip_atomic_load(&slotq[i], __ATOMIC_RELAXED, __HIP_MEMORY_SCOPE_AGENT)
             : 0.0;
      #pragma unroll
      for (int i = 0; i < 15; ++i) {
        d[i] += __shfl_xor(d[i], 1);
        d[i] += __shfl_xor(d[i], 2);
        d[i] += __shfl_xor(d[i], 4);
        d[i] += __shfl_xor(d[i], 8);
        d[i] += __shfl_xor(d[i], 16);
      }

      if (lane == 0) {
        const double inv = 1.0 / (double)NP;
        const double cs0=d[0]*inv, cs1=d[1]*inv, cs2=d[2]*inv;
        const double ct0=d[3]*inv, ct1=d[4]*inv, ct2=d[5]*inv;
        float M[9];
        M[0]=(float)(d[6] -(double)NP*ct0*cs0); M[1]=(float)(d[7] -(double)NP*ct0*cs1); M[2]=(float)(d[8] -(double)NP*ct0*cs2);
        M[3]=(float)(d[9] -(double)NP*ct1*cs0); M[4]=(float)(d[10]-(double)NP*ct1*cs1); M[5]=(float)(d[11]-(double)NP*ct1*cs2);
        M[6]=(float)(d[12]-(double)NP*ct2*cs0); M[7]=(float)(d[13]-(double)NP*ct2*cs1); M[8]=(float)(d[14]-(double)NP*ct2*cs2);
        float R[9]; polar3x3f(M, R);
        #pragma unroll
        for (int i = 0; i < 9; ++i) s_rt[i] = R[i];
        s_rt[9]  = (float)(ct0 - ((double)R[0]*cs0 + (double)R[1]*cs1 + (double)R[2]*cs2));
        s_rt[10] = (float)(ct1 - ((double)R[3]*cs0 + (double)R[4]*cs1 + (double)R[5]*cs2));
        s_rt[11] = (float)(ct2 - ((double)R[6]*cs0 + (double)R[7]*cs1 + (double)R[8]*cs2));
      }
    }
    __syncthreads();

    // ---- apply transform to this wave's temporal points (fp32, like ref) ----
    {
      const float R00=s_rt[0],R01=s_rt[1],R02=s_rt[2],
                  R10=s_rt[3],R11=s_rt[4],R12=s_rt[5],
                  R20=s_rt[6],R21=s_rt[7],R22=s_rt[8],
                  t0=s_rt[9], t1=s_rt[10], t2=s_rt[11];
      #pragma unroll
      for (int r = 0; r < 8; ++r) {
        const float nx = t0 + R00*px[r] + R01*py[r] + R02*pz[r];
        const float ny = t1 + R10*px[r] + R11*py[r] + R12*pz[r];
        const float nz = t2 + R20*px[r] + R21*py[r] + R22*pz[r];
        px[r]=nx; py[r]=ny; pz[r]=nz;
      }
    }
  }

  // ---- final Kabsch: original source -> final temporal (parity 0, want 9) ----
  {
    float S[15];
    #pragma unroll
    for (int i = 0; i < 15; ++i) S[i] = 0.f;
    const float* sb2 = src + (size_t)(batch * NP + r0) * 3;
    #pragma unroll
    for (int r = 0; r < 8; ++r) {
      const float ox = sb2[3*r+0], oy = sb2[3*r+1], oz = sb2[3*r+2];
      S[0]+=ox; S[1]+=oy; S[2]+=oz;
      S[3]+=px[r]; S[4]+=py[r]; S[5]+=pz[r];
      S[6] +=px[r]*ox; S[7] +=px[r]*oy; S[8] +=px[r]*oz;
      S[9] +=py[r]*ox; S[10]+=py[r]*oy; S[11]+=py[r]*oz;
      S[12]+=pz[r]*ox; S[13]+=pz[r]*oy; S[14]+=pz[r]*oz;
    }
    if (lane == 0) {
      #pragma unroll
      for (int i = 0; i < 15; ++i) s_part[wave][i] = S[i];
    }
  }
  __syncthreads();

  if (wave == 0) {
    const unsigned want = (unsigned)(NITER + 1);
    const int comp = lane & 15, grp = lane >> 4;
    float v = (comp < 15) ? (s_part[2*grp][comp] + s_part[2*grp+1][comp]) : 0.f;
    v += __shfl_xor(v, 16);
    v += __shfl_xor(v, 32);
    float Sv[15];
    #pragma unroll
    for (int i = 0; i < 15; ++i) Sv[i] = __shfl(v, i);
    float* slotMine = ws + (((size_t)batch * WPB + w) << 4);   // parity 0
    if (lane == 0) {
      #pragma unroll
      for (int i = 0; i < 15; ++i)
        __hip_atomic_store(&slotMine[i], Sv[i], __ATOMIC_RELAXED, __HIP_MEMORY_SCOPE_AGENT);
      __hip_atomic_store((unsigned*)slotMine + 15, want,
                         __ATOMIC_RELEASE, __HIP_MEMORY_SCOPE_AGENT);
    }

    if (w == 0) {
      float* base = ws + ((size_t)batch * WPB << 4);
      unsigned* sentq = (unsigned*)(base + ((size_t)lane << 4)) + 15;
      int ok;
      do {
        ok = (lane >= WPB) ||
             (__hip_atomic_load(sentq, __ATOMIC_ACQUIRE, __HIP_MEMORY_SCOPE_AGENT) == want);
      } while (!__all(ok));

      const float* slotq = base + ((size_t)lane << 4);
      double d[15];
      #pragma unroll
      for (int i = 0; i < 15; ++i)
        d[i] = (lane < WPB)
             ? (double)__hip_atomic_load(&slotq[i], __ATOMIC_RELAXED, __HIP_MEMORY_SCOPE_AGENT)
             : 0.0;
      #pragma unroll
      for (int i = 0; i < 15; ++i) {
        d[i] += __shfl_xor(d[i], 1);
        d[i] += __shfl_xor(d[i], 2);
        d[i] += __shfl_xor(d[i], 4);
        d[i] += __shfl_xor(d[i], 8);
        d[i] += __shfl_xor(d[i], 16);
      }

      if (lane == 0) {
        const double inv = 1.0 / (double)NP;
        const double cs0=d[0]*inv, cs1=d[1]*inv, cs2=d[2]*inv;
        const double ct0=d[3]*inv, ct1=d[4]*inv, ct2=d[5]*inv;
        float M[9];
        M[0]=(float)(d[6] -(double)NP*ct0*cs0); M[1]=(float)(d[7] -(double)NP*ct0*cs1); M[2]=(float)(d[8] -(double)NP*ct0*cs2);
        M[3]=(float)(d[9] -(double)NP*ct1*cs0); M[4]=(float)(d[10]-(double)NP*ct1*cs1); M[5]=(float)(d[11]-(double)NP*ct1*cs2);
        M[6]=(float)(d[12]-(double)NP*ct2*cs0); M[7]=(float)(d[13]-(double)NP*ct2*cs1); M[8]=(float)(d[14]-(double)NP*ct2*cs2);
        float R[9]; polar3x3f(M, R);
        const double t0 = ct0 - ((double)R[0]*cs0 + (double)R[1]*cs1 + (double)R[2]*cs2);
        const double t1 = ct1 - ((double)R[3]*cs0 + (double)R[4]*cs1 + (double)R[5]*cs2);
        const double t2 = ct2 - ((double)R[6]*cs0 + (double)R[7]*cs1 + (double)R[8]*cs2);
        float* ob = out + batch * 12;
        ob[0]=R[0]; ob[1]=R[1]; ob[2] =R[2]; ob[3] =(float)t0;
        ob[4]=R[3]; ob[5]=R[4]; ob[6] =R[5]; ob[7] =(float)t1;
        ob[8]=R[6]; ob[9]=R[7]; ob[10]=R[8]; ob[11]=(float)t2;
      }
    }
  }
}

extern "C" void kernel_launch(void* const* d_in, const int* in_sizes, int n_in,
                              void* d_out, int out_size, void* d_ws, size_t ws_size,
                              hipStream_t stream)
{
  const float* src = (const float*)d_in[0];
  const float* tgt = (const float*)d_in[1];
  float* out = (float*)d_out;
  float* ws  = (float*)d_ws;

  // zero the whole slot region (partials + sentinels) each call:
  // deterministic from poisoned ws and across graph replays.
  hipMemsetAsync(d_ws, 0, 2 * NB * WPB * 16 * sizeof(float), stream);

  void* args[] = { (void*)&src, (void*)&tgt, (void*)&out, (void*)&ws };
  hipLaunchCooperativeKernel(reinterpret_cast<void*>(icp_kernel),
                             dim3(NB * WPB), dim3(NT), args, 0, stream);
}

// Round 5
// 176.787 us; speedup vs baseline: 2.3121x; 1.2017x over previous
//
#include <hip/hip_runtime.h>

#define NB     8      // batches
#define NP     2048   // points per cloud
#define NITER  8
#define WPB    32     // workgroups per batch (grid = NB*WPB = 256, coop-launch max)
#define NT     512    // threads per workgroup (8 waves)
#define TSTEPS 32     // targets per lane = NP / 64
#define BCAST_OFF (2*NB*WPB*16)  // float offset of broadcast lines (8192)

// ws layout (floats):
//   slots : [2 parity][NB][WPB][16]   (slot[0..14] partials, slot[15] uint sentinel)
//   bcast : [NB][16] at BCAST_OFF     (bl[0..8]=R, bl[9..11]=t, bl[15] uint tag)
// whole region hipMemsetAsync(0) each call -> replay-deterministic.
// Server role: wave 0 of each batch's w==0 WG (wg 0..7). Workers w=1..31
// publish slots; server polls 31 slots, reduces, runs polar, broadcasts,
// composes the total transform, and writes the output (replaces final Kabsch:
// temporal_8 is an exact rigid transform of source, so svdtf(source,temporal_8)
// == composed transform; det=+1 so the reference's reflection branch is a no-op).

// Orthogonal polar factor of M (== U @ Vh of the SVD) in fp32, with the
// reference's reflection handling (R = -R when det = -1). Det-scaled Newton.
__device__ void polar3x3f(const float* Min, float* R) {
  float X[9];
  #pragma unroll
  for (int i = 0; i < 9; ++i) X[i] = Min[i];
  #pragma unroll 1
  for (int it = 0; it < 12; ++it) {
    const float C0 = X[4]*X[8]-X[5]*X[7];
    const float C1 = X[5]*X[6]-X[3]*X[8];
    const float C2 = X[3]*X[7]-X[4]*X[6];
    const float C3 = X[2]*X[7]-X[1]*X[8];
    const float C4 = X[0]*X[8]-X[2]*X[6];
    const float C5 = X[1]*X[6]-X[0]*X[7];
    const float C6 = X[1]*X[5]-X[2]*X[4];
    const float C7 = X[2]*X[3]-X[0]*X[5];
    const float C8 = X[0]*X[4]-X[1]*X[3];
    const float det = X[0]*C0 + X[1]*C1 + X[2]*C2;
    const float ad  = fabsf(det);
    const float g   = (ad > 1e-30f) ? exp2f(-0.33333333333f * log2f(ad)) : 1.0f;
    const float ds  = (ad > 1e-30f) ? det : 1e-30f;
    const float h   = 0.5f / (g * ds);     // X' = 0.5*g*X + cof(X)/(2*g*det)
    const float gh  = 0.5f * g;
    X[0]=gh*X[0]+h*C0; X[1]=gh*X[1]+h*C1; X[2]=gh*X[2]+h*C2;
    X[3]=gh*X[3]+h*C3; X[4]=gh*X[4]+h*C4; X[5]=gh*X[5]+h*C5;
    X[6]=gh*X[6]+h*C6; X[7]=gh*X[7]+h*C7; X[8]=gh*X[8]+h*C8;
  }
  const float d = X[0]*(X[4]*X[8]-X[5]*X[7])
                + X[1]*(X[5]*X[6]-X[3]*X[8])
                + X[2]*(X[3]*X[7]-X[4]*X[6]);
  const float s = (d < 0.0f) ? -1.0f : 1.0f;
  #pragma unroll
  for (int i = 0; i < 9; ++i) R[i] = s * X[i];
}

__global__ __launch_bounds__(NT, 2)
void icp_kernel(const float* __restrict__ src, const float* __restrict__ tgt,
                float* __restrict__ out, float* __restrict__ ws)
{
  __shared__ float4 s_tgt[NP];        // 32 KB: {x,y,z, 0.5*|t|^2}
  __shared__ float  s_part[8][16];    // per-wave partial sums
  __shared__ float  s_rt[12];         // R (9) + t (3) broadcast within WG

  const int tid   = threadIdx.x;
  const int wg    = blockIdx.x;
  const int batch = wg & 7;           // XCD-swizzle: one batch's WGs share an XCD
  const int w     = wg >> 3;
  const int wave  = tid >> 6;
  const int lane  = tid & 63;
  const bool isServerWG = (w == 0);

  // server-only state (lane 0 of wave 0 of wg 0..7); cheap registers elsewhere
  float Rtot[9] = {1.f,0.f,0.f, 0.f,1.f,0.f, 0.f,0.f,1.f};
  float ttot[3] = {0.f,0.f,0.f};

  // ---- stage targets in LDS; .w = 0.5*|t|^2 for the score trick ----
  const float* tb = tgt + (size_t)batch * NP * 3;
  for (int i = tid; i < NP; i += NT) {
    const float tx = tb[3*i+0], ty = tb[3*i+1], tz = tb[3*i+2];
    s_tgt[i] = make_float4(tx, ty, tz, 0.5f*(tx*tx + ty*ty + tz*tz));
  }

  // ---- this wave's 8 temporal points (replicated across lanes) ----
  const int r0 = w * 64 + wave * 8;
  const float* sb = src + (size_t)(batch * NP + r0) * 3;
  float px[8], py[8], pz[8];
  #pragma unroll
  for (int r = 0; r < 8; ++r) {
    px[r] = sb[3*r+0]; py[r] = sb[3*r+1]; pz[r] = sb[3*r+2];
  }
  __syncthreads();

  float* bl = ws + BCAST_OFF + batch * 16;

  for (int round = 0; round < NITER; ++round) {
    const int      par  = round & 1;
    const unsigned want = (unsigned)(round + 1);

    // ---- KNN via score = 0.5|t|^2 - p.t  (argmin(score) == argmin(dist)) ----
    float bs[8]; int bj[8];
    #pragma unroll
    for (int r = 0; r < 8; ++r) { bs[r] = 3.4e38f; bj[r] = 0; }
    #pragma unroll 4
    for (int k = 0; k < TSTEPS; ++k) {
      const int j = k * 64 + lane;
      const float4 tp = s_tgt[j];
      #pragma unroll
      for (int r = 0; r < 8; ++r) {
        const float sc = fmaf(-px[r], tp.x, fmaf(-py[r], tp.y, fmaf(-pz[r], tp.z, tp.w)));
        if (sc < bs[r]) { bs[r] = sc; bj[r] = j; }   // strict < keeps first index
      }
    }
    // cross-lane argmin, tie -> smaller index (matches argmin first-index rule)
    #pragma unroll
    for (int r = 0; r < 8; ++r) {
      #pragma unroll
      for (int sh = 0; sh < 6; ++sh) {
        const int   off = 32 >> sh;
        const float od  = __shfl_xor(bs[r], off);
        const int   oj  = __shfl_xor(bj[r], off);
        if (od < bs[r] || (od == bs[r] && oj < bj[r])) { bs[r] = od; bj[r] = oj; }
      }
    }

    // ---- per-wave Kabsch partials (identical in every lane; lane 0 writes) ----
    {
      float S[15];
      #pragma unroll
      for (int i = 0; i < 15; ++i) S[i] = 0.f;
      #pragma unroll
      for (int r = 0; r < 8; ++r) {
        const float4 tm = s_tgt[bj[r]];
        S[0]+=px[r]; S[1]+=py[r]; S[2]+=pz[r];
        S[3]+=tm.x;  S[4]+=tm.y;  S[5]+=tm.z;
        S[6] +=tm.x*px[r]; S[7] +=tm.x*py[r]; S[8] +=tm.x*pz[r];
        S[9] +=tm.y*px[r]; S[10]+=tm.y*py[r]; S[11]+=tm.y*pz[r];
        S[12]+=tm.z*px[r]; S[13]+=tm.z*py[r]; S[14]+=tm.z*pz[r];
      }
      if (lane == 0) {
        #pragma unroll
        for (int i = 0; i < 15; ++i) s_part[wave][i] = S[i];
      }
    }
    __syncthreads();

    if (wave == 0) {
      // ---- fold 8 wave-partials: every lane ends with total for comp=lane&15 ----
      const int comp = lane & 15, grp = lane >> 4;
      float v = (comp < 15) ? (s_part[2*grp][comp] + s_part[2*grp+1][comp]) : 0.f;
      v += __shfl_xor(v, 16);
      v += __shfl_xor(v, 32);
      float Sv[15];
      #pragma unroll
      for (int i = 0; i < 15; ++i) Sv[i] = __shfl(v, i);

      if (!isServerWG) {
        // ---- worker: lane 0 publishes slot + release sentinel ----
        float* slotMine = ws + ((((size_t)par * NB + batch) * WPB + w) << 4);
        if (lane == 0) {
          #pragma unroll
          for (int i = 0; i < 15; ++i)
            __hip_atomic_store(&slotMine[i], Sv[i], __ATOMIC_RELAXED, __HIP_MEMORY_SCOPE_AGENT);
          __hip_atomic_store((unsigned*)slotMine + 15, want,
                             __ATOMIC_RELEASE, __HIP_MEMORY_SCOPE_AGENT);
        }
        if (round < NITER - 1) {
          // spin on the broadcast line (wave 0 only; other waves at barrier)
          unsigned* tag = (unsigned*)bl + 15;
          while (__hip_atomic_load(tag, __ATOMIC_RELAXED, __HIP_MEMORY_SCOPE_AGENT) != want) {}
          __builtin_amdgcn_fence(__ATOMIC_ACQUIRE, "agent");
          const float rb = (lane < 12)
              ? __hip_atomic_load(&bl[lane], __ATOMIC_RELAXED, __HIP_MEMORY_SCOPE_AGENT)
              : 0.f;
          if (lane < 12) s_rt[lane] = rb;
        }
      } else {
        // ---- server: poll the other 31 slots (lane q watches slot q) ----
        float* base = ws + (((size_t)par * NB + batch) * WPB << 4);
        unsigned* sentq = (unsigned*)(base + ((size_t)lane << 4)) + 15;
        const bool polls = (lane >= 1) && (lane < WPB);
        int ok;
        do {
          ok = !polls ||
               (__hip_atomic_load(sentq, __ATOMIC_RELAXED, __HIP_MEMORY_SCOPE_AGENT) == want);
        } while (!__all(ok));
        __builtin_amdgcn_fence(__ATOMIC_ACQUIRE, "agent");

        const float* slotq = base + ((size_t)lane << 4);
        float s[15];
        #pragma unroll
        for (int i = 0; i < 15; ++i) {
          float t = polls
              ? __hip_atomic_load(&slotq[i], __ATOMIC_RELAXED, __HIP_MEMORY_SCOPE_AGENT)
              : 0.f;
          s[i] = (lane == 0) ? Sv[i] : t;   // own WG's partial stays in registers
        }
        #pragma unroll
        for (int i = 0; i < 15; ++i) {
          s[i] += __shfl_xor(s[i], 1);
          s[i] += __shfl_xor(s[i], 2);
          s[i] += __shfl_xor(s[i], 4);
          s[i] += __shfl_xor(s[i], 8);
          s[i] += __shfl_xor(s[i], 16);
        }

        if (lane == 0) {
          const double inv = 1.0 / (double)NP;
          const double cs0=(double)s[0]*inv, cs1=(double)s[1]*inv, cs2=(double)s[2]*inv;
          const double ct0=(double)s[3]*inv, ct1=(double)s[4]*inv, ct2=(double)s[5]*inv;
          float M[9];
          M[0]=(float)((double)s[6] -(double)NP*ct0*cs0); M[1]=(float)((double)s[7] -(double)NP*ct0*cs1); M[2]=(float)((double)s[8] -(double)NP*ct0*cs2);
          M[3]=(float)((double)s[9] -(double)NP*ct1*cs0); M[4]=(float)((double)s[10]-(double)NP*ct1*cs1); M[5]=(float)((double)s[11]-(double)NP*ct1*cs2);
          M[6]=(float)((double)s[12]-(double)NP*ct2*cs0); M[7]=(float)((double)s[13]-(double)NP*ct2*cs1); M[8]=(float)((double)s[14]-(double)NP*ct2*cs2);
          float R[9]; polar3x3f(M, R);
          const float t0 = (float)(ct0 - ((double)R[0]*cs0 + (double)R[1]*cs1 + (double)R[2]*cs2));
          const float t1 = (float)(ct1 - ((double)R[3]*cs0 + (double)R[4]*cs1 + (double)R[5]*cs2));
          const float t2 = (float)(ct2 - ((double)R[6]*cs0 + (double)R[7]*cs1 + (double)R[8]*cs2));

          if (round < NITER - 1) {
            // publish broadcast for the other 31 WGs
            #pragma unroll
            for (int i = 0; i < 9; ++i)
              __hip_atomic_store(&bl[i], R[i], __ATOMIC_RELAXED, __HIP_MEMORY_SCOPE_AGENT);
            __hip_atomic_store(&bl[9],  t0, __ATOMIC_RELAXED, __HIP_MEMORY_SCOPE_AGENT);
            __hip_atomic_store(&bl[10], t1, __ATOMIC_RELAXED, __HIP_MEMORY_SCOPE_AGENT);
            __hip_atomic_store(&bl[11], t2, __ATOMIC_RELAXED, __HIP_MEMORY_SCOPE_AGENT);
            __hip_atomic_store((unsigned*)bl + 15, want,
                               __ATOMIC_RELEASE, __HIP_MEMORY_SCOPE_AGENT);
            // own-WG broadcast via LDS
            s_rt[0]=R[0]; s_rt[1]=R[1]; s_rt[2]=R[2];
            s_rt[3]=R[3]; s_rt[4]=R[4]; s_rt[5]=R[5];
            s_rt[6]=R[6]; s_rt[7]=R[7]; s_rt[8]=R[8];
            s_rt[9]=t0;  s_rt[10]=t1;  s_rt[11]=t2;
          }

          // compose total transform: T_tot <- T_round ∘ T_tot
          float Rn[9], tn[3];
          #pragma unroll
          for (int i = 0; i < 3; ++i) {
            Rn[3*i+0] = R[3*i+0]*Rtot[0] + R[3*i+1]*Rtot[3] + R[3*i+2]*Rtot[6];
            Rn[3*i+1] = R[3*i+0]*Rtot[1] + R[3*i+1]*Rtot[4] + R[3*i+2]*Rtot[7];
            Rn[3*i+2] = R[3*i+0]*Rtot[2] + R[3*i+1]*Rtot[5] + R[3*i+2]*Rtot[8];
            tn[i]     = R[3*i+0]*ttot[0] + R[3*i+1]*ttot[1] + R[3*i+2]*ttot[2]
                      + ((i==0)?t0:(i==1)?t1:t2);
          }
          #pragma unroll
          for (int i = 0; i < 9; ++i) Rtot[i] = Rn[i];
          ttot[0]=tn[0]; ttot[1]=tn[1]; ttot[2]=tn[2];

          if (round == NITER - 1) {
            float* ob = out + batch * 12;
            ob[0]=Rtot[0]; ob[1]=Rtot[1]; ob[2] =Rtot[2]; ob[3] =ttot[0];
            ob[4]=Rtot[3]; ob[5]=Rtot[4]; ob[6] =Rtot[5]; ob[7] =ttot[1];
            ob[8]=Rtot[6]; ob[9]=Rtot[7]; ob[10]=Rtot[8]; ob[11]=ttot[2];
          }
        }
      }
    }

    if (round < NITER - 1) {
      __syncthreads();
      // ---- apply transform to this wave's temporal points (fp32, like ref) ----
      const float R00=s_rt[0],R01=s_rt[1],R02=s_rt[2],
                  R10=s_rt[3],R11=s_rt[4],R12=s_rt[5],
                  R20=s_rt[6],R21=s_rt[7],R22=s_rt[8],
                  t0=s_rt[9], t1=s_rt[10], t2=s_rt[11];
      #pragma unroll
      for (int r = 0; r < 8; ++r) {
        const float nx = t0 + R00*px[r] + R01*py[r] + R02*pz[r];
        const float ny = t1 + R10*px[r] + R11*py[r] + R12*pz[r];
        const float nz = t2 + R20*px[r] + R21*py[r] + R22*pz[r];
        px[r]=nx; py[r]=ny; pz[r]=nz;
      }
    }
    // last round: workers just published; server composed and wrote the output.
  }
}

extern "C" void kernel_launch(void* const* d_in, const int* in_sizes, int n_in,
                              void* d_out, int out_size, void* d_ws, size_t ws_size,
                              hipStream_t stream)
{
  const float* src = (const float*)d_in[0];
  const float* tgt = (const float*)d_in[1];
  float* out = (float*)d_out;
  float* ws  = (float*)d_ws;

  // zero slots + broadcast lines each call: deterministic across graph replays
  hipMemsetAsync(d_ws, 0, (BCAST_OFF + NB * 16) * sizeof(float), stream);

  void* args[] = { (void*)&src, (void*)&tgt, (void*)&out, (void*)&ws };
  hipLaunchCooperativeKernel(reinterpret_cast<void*>(icp_kernel),
                             dim3(NB * WPB), dim3(NT), args, 0, stream);
}